// Round 18
// baseline (1061.756 us; speedup 1.0000x reference)
//
#include <hip/hip_runtime.h>
#include <cstdint>

#define KNN 20
#define BV 8
#define NV 1024

// ---- DPP wave64 reduces (rocPRIM pattern): result broadcast via readlane 63.
template <int CTRL>
__device__ __forceinline__ float dppmaxf(float x) {
    int xi = __float_as_int(x);
    int mi = __builtin_amdgcn_update_dpp(xi, xi, CTRL, 0xf, 0xf, false);
    return fmaxf(x, __int_as_float(mi));
}
template <int CTRL>
__device__ __forceinline__ unsigned dppmin(unsigned x) {
    unsigned m = (unsigned)__builtin_amdgcn_update_dpp((int)x, (int)x, CTRL, 0xf, 0xf, false);
    return (x < m) ? x : m;
}
__device__ __forceinline__ float wave_max_f32(float x) {
    x = dppmaxf<0xB1>(x); x = dppmaxf<0x4E>(x); x = dppmaxf<0x141>(x);
    x = dppmaxf<0x140>(x); x = dppmaxf<0x142>(x); x = dppmaxf<0x143>(x);
    return __int_as_float(__builtin_amdgcn_readlane(__float_as_int(x), 63));
}
__device__ __forceinline__ unsigned wave_min_u32(unsigned x) {
    x = dppmin<0xB1>(x); x = dppmin<0x4E>(x); x = dppmin<0x141>(x);
    x = dppmin<0x140>(x); x = dppmin<0x142>(x); x = dppmin<0x143>(x);
    return (unsigned)__builtin_amdgcn_readlane((int)x, 63);
}

// ---------- transpose x [B,N,3] -> hx [B,3,N]
__global__ __launch_bounds__(256) void k_transpose(const float* __restrict__ x, float* __restrict__ hx) {
    int id = blockIdx.x * 256 + threadIdx.x;
    if (id >= BV * 3 * NV) return;
    int n = id % NV;
    int c = (id / NV) % 3;
    int b = id / (3 * NV);
    hx[id] = x[(b * NV + n) * 3 + c];
}

// ---------- xx[b][n] = sum_c h[b][c][n]^2
__global__ __launch_bounds__(256) void k_xx(const float* __restrict__ h, float* __restrict__ xx,
                                            int C, int bstride) {
    int id = blockIdx.x * 256 + threadIdx.x;
    int n = id % NV, b = id / NV;
    if (b >= BV) return;
    const float* hp = h + (size_t)b * bstride + n;
    float s = 0.f;
    for (int c = 0; c < C; ++c) { float v = hp[(size_t)c * NV]; s += v * v; }
    xx[b * NV + n] = s;
}

// ---------- FULL-ROW kNN (L0-L2): block = 16 rows x 1024 cols; 8 waves, 2 rows/wave;
// lane owns 16 cands at j = g*256+lane*4+e (conflict-free b128). A-side (2 rows x 8 ch)
// in registers from global (wave-uniform, L2 broadcast) -> 4 DS reads/channel, not 5.
__global__ __launch_bounds__(512, 2) void k_knnF(const float* __restrict__ h, const float* __restrict__ xx,
                                                 int C, int bstride, int* __restrict__ idx) {
    __shared__ float Bs[8][1024];
    const int bx = blockIdx.x;
    const int b = bx & 7, tile = bx >> 3;
    const int i0 = tile * 16;
    const int t = threadIdx.x, lane = t & 63, w = t >> 6;
    const int irow = i0 + w * 2;
    float acc[2][16] = {};
    const float* hb = h + (size_t)b * bstride;

    for (int c0 = 0; c0 < C; c0 += 8) {
        __syncthreads();
#pragma unroll
        for (int r = 0; r < 4; ++r) {               // Bs[8][1024] = 2048 float4 granules
            int e = r * 512 + t;
            int cc = e >> 8, jj = e & 255;
            float4 v = make_float4(0.f, 0.f, 0.f, 0.f);
            if (c0 + cc < C) v = *(const float4*)&hb[(size_t)(c0 + cc) * NV + jj * 4];
            *(float4*)&Bs[cc][jj * 4] = v;
        }
        float2 ar2[8];                              // A rows in regs (wave-uniform b64)
#pragma unroll
        for (int cc = 0; cc < 8; ++cc) {
            ar2[cc] = make_float2(0.f, 0.f);
            if (c0 + cc < C) ar2[cc] = *(const float2*)&hb[(size_t)(c0 + cc) * NV + irow];
        }
        __syncthreads();
#pragma unroll
        for (int c = 0; c < 8; ++c) {
            float ar[2] = {ar2[c].x, ar2[c].y};
            float br[16];
#pragma unroll
            for (int g = 0; g < 4; ++g) {
                float4 bv = *(const float4*)&Bs[c][g * 256 + (lane << 2)];  // conflict-free
                br[g * 4 + 0] = bv.x; br[g * 4 + 1] = bv.y;
                br[g * 4 + 2] = bv.z; br[g * 4 + 3] = bv.w;
            }
#pragma unroll
            for (int a = 0; a < 2; ++a)
#pragma unroll
                for (int q = 0; q < 16; ++q) acc[a][q] += ar[a] * br[q];
        }
    }

    // neg sqdist in place: bigger = nearer
    const float* xb = xx + b * NV;
    float xxj[16];
#pragma unroll
    for (int g = 0; g < 4; ++g) {
        float4 xv = *(const float4*)&xb[g * 256 + (lane << 2)];
        xxj[g * 4 + 0] = xv.x; xxj[g * 4 + 1] = xv.y;
        xxj[g * 4 + 2] = xv.z; xxj[g * 4 + 3] = xv.w;
    }
#pragma unroll
    for (int a = 0; a < 2; ++a) {
        float xi = xb[irow + a];
#pragma unroll
        for (int q = 0; q < 16; ++q) acc[a][q] = 2.f * acc[a][q] - xi - xxj[q];
    }

    // wave-parallel top-20 per row, 2 rows interleaved
    int* opb = idx + ((size_t)(b * NV + irow)) * KNN;
#pragma unroll 1
    for (int s = 0; s < KNN; ++s) {
#pragma unroll
        for (int a = 0; a < 2; ++a) {
            float w0[8]; int p0[8];
#pragma unroll
            for (int i = 0; i < 8; ++i) {
                bool g = acc[a][2 * i + 1] > acc[a][2 * i];
                w0[i] = g ? acc[a][2 * i + 1] : acc[a][2 * i];
                p0[i] = g ? 2 * i + 1 : 2 * i;
            }
            float w1[4]; int p1[4];
#pragma unroll
            for (int i = 0; i < 4; ++i) {
                bool g = w0[2 * i + 1] > w0[2 * i];
                w1[i] = g ? w0[2 * i + 1] : w0[2 * i];
                p1[i] = g ? p0[2 * i + 1] : p0[2 * i];
            }
            float w2[2]; int p2[2];
#pragma unroll
            for (int i = 0; i < 2; ++i) {
                bool g = w1[2 * i + 1] > w1[2 * i];
                w2[i] = g ? w1[2 * i + 1] : w1[2 * i];
                p2[i] = g ? p1[2 * i + 1] : p1[2 * i];
            }
            bool gf = w2[1] > w2[0];
            float bv = gf ? w2[1] : w2[0];
            int bq = gf ? p2[1] : p2[0];

            float gmax = wave_max_f32(bv);
            int myj = ((bq >> 2) << 8) + (lane << 2) + (bq & 3);
            unsigned cand = (bv == gmax) ? (unsigned)myj : 0xFFFFFFFFu;
            int j = (int)wave_min_u32(cand);            // exact lowest-j among value ties
            if (lane == 0) opb[a * KNN + s] = j;
            int wq = (cand == (unsigned)j) ? bq : 99;
#pragma unroll
            for (int q = 0; q < 16; ++q)
                if (wq == q) acc[a][q] = -3.4e38f;
        }
    }
}

// ---------- j-SPLIT kNN (Lf): 8 waves = 4 rowgroups x 2 j-halves; 4 rows/wave, 8 j/lane;
// A-side (4 rows x 8 ch) in registers from global -> 2 DS reads/channel (was 3).
// Per-half sorted top-20 -> LDS -> exact 2-list merge (val desc, j asc).
__global__ __launch_bounds__(512, 2) void k_knnS(const float* __restrict__ h, const float* __restrict__ xx,
                                                 int C, int bstride, int* __restrict__ idx) {
    __shared__ float Bs[8][1024];
    __shared__ float sv[16][2][KNN];
    __shared__ int   sj[16][2][KNN];
    const int bx = blockIdx.x;
    const int b = bx & 7, tile = bx >> 3;
    const int i0 = tile * 16;
    const int t = threadIdx.x, lane = t & 63, w = t >> 6;
    const int rg = w & 3, hf = w >> 2;
    const int irow = i0 + rg * 4;
    const int jb = hf * 512;
    float acc[4][8] = {};
    const float* hb = h + (size_t)b * bstride;

    for (int c0 = 0; c0 < C; c0 += 8) {
        __syncthreads();
#pragma unroll
        for (int r = 0; r < 4; ++r) {
            int e = r * 512 + t;
            int cc = e >> 8, jj = e & 255;
            float4 v = make_float4(0.f, 0.f, 0.f, 0.f);
            if (c0 + cc < C) v = *(const float4*)&hb[(size_t)(c0 + cc) * NV + jj * 4];
            *(float4*)&Bs[cc][jj * 4] = v;
        }
        float4 ar8[8];                              // A rows in regs (wave-uniform b128)
#pragma unroll
        for (int cc = 0; cc < 8; ++cc) {
            ar8[cc] = make_float4(0.f, 0.f, 0.f, 0.f);
            if (c0 + cc < C) ar8[cc] = *(const float4*)&hb[(size_t)(c0 + cc) * NV + irow];
        }
        __syncthreads();
#pragma unroll
        for (int c = 0; c < 8; ++c) {
            float ar[4] = {ar8[c].x, ar8[c].y, ar8[c].z, ar8[c].w};
            float br[8];
#pragma unroll
            for (int g = 0; g < 2; ++g) {
                float4 bv = *(const float4*)&Bs[c][jb + g * 256 + (lane << 2)];  // conflict-free
                br[g * 4 + 0] = bv.x; br[g * 4 + 1] = bv.y;
                br[g * 4 + 2] = bv.z; br[g * 4 + 3] = bv.w;
            }
#pragma unroll
            for (int a = 0; a < 4; ++a)
#pragma unroll
                for (int q = 0; q < 8; ++q) acc[a][q] += ar[a] * br[q];
        }
    }

    // neg sqdist in place
    const float* xb = xx + b * NV;
    float xxj[8];
#pragma unroll
    for (int g = 0; g < 2; ++g) {
        float4 xv = *(const float4*)&xb[jb + g * 256 + (lane << 2)];
        xxj[g * 4 + 0] = xv.x; xxj[g * 4 + 1] = xv.y;
        xxj[g * 4 + 2] = xv.z; xxj[g * 4 + 3] = xv.w;
    }
#pragma unroll
    for (int a = 0; a < 4; ++a) {
        float xi = xb[irow + a];
#pragma unroll
        for (int q = 0; q < 8; ++q) acc[a][q] = 2.f * acc[a][q] - xi - xxj[q];
    }

    // per-half wave-parallel top-20, 4 rows interleaved; sorted (val desc, j asc)
#pragma unroll 1
    for (int s = 0; s < KNN; ++s) {
#pragma unroll
        for (int a = 0; a < 4; ++a) {
            float w0[4]; int p0[4];
#pragma unroll
            for (int i = 0; i < 4; ++i) {
                bool g = acc[a][2 * i + 1] > acc[a][2 * i];
                w0[i] = g ? acc[a][2 * i + 1] : acc[a][2 * i];
                p0[i] = g ? 2 * i + 1 : 2 * i;
            }
            float w1[2]; int p1[2];
#pragma unroll
            for (int i = 0; i < 2; ++i) {
                bool g = w0[2 * i + 1] > w0[2 * i];
                w1[i] = g ? w0[2 * i + 1] : w0[2 * i];
                p1[i] = g ? p0[2 * i + 1] : p0[2 * i];
            }
            bool gf = w1[1] > w1[0];
            float bv = gf ? w1[1] : w1[0];
            int bq = gf ? p1[1] : p1[0];

            float gmax = wave_max_f32(bv);
            int myj = jb + ((bq >> 2) << 8) + (lane << 2) + (bq & 3);
            unsigned cand = (bv == gmax) ? (unsigned)myj : 0xFFFFFFFFu;
            int j = (int)wave_min_u32(cand);
            if (lane == 0) {
                sv[rg * 4 + a][hf][s] = gmax;
                sj[rg * 4 + a][hf][s] = j;
            }
            int wq = (cand == (unsigned)j) ? bq : 99;
#pragma unroll
            for (int q = 0; q < 8; ++q)
                if (wq == q) acc[a][q] = -3.4e38f;
        }
    }

    __syncthreads();
    if (t < 16) {   // exact 2-list merge per row
        const float* v0 = sv[t][0];
        const float* v1 = sv[t][1];
        const int* j0 = sj[t][0];
        const int* j1 = sj[t][1];
        int* op = idx + ((size_t)(b * NV + i0 + t)) * KNN;
        int a = 0, c2 = 0;
#pragma unroll
        for (int s = 0; s < KNN; ++s) {
            float va = v0[a], vb = v1[c2];
            int ja = j0[a], jb2 = j1[c2];
            bool take0 = (va > vb) || (va == vb && ja < jb2);
            op[s] = take0 ? ja : jb2;
            a += take0 ? 1 : 0;
            c2 += take0 ? 0 : 1;
        }
    }
}

// ---------- pd[b][r][n] = sum_c A[r][c]*h[b][c][n], A packed inline from W:
// r<O: Wl row; r>=O: (Wr-Wl) row.   64x128 tile, 4x8 micro.
__global__ __launch_bounds__(256) void k_gemm(const float* __restrict__ W, int O,
                                              const float* __restrict__ h, int bstride, int C,
                                              float* __restrict__ out) {
    __shared__ float Ws[8][64], Hs[8][128];
    const int b = blockIdx.x, n0 = blockIdx.y * 128, o0 = blockIdx.z * 64;
    const int t = threadIdx.x, tx = t & 15, ty = t >> 4;
    float acc[4][8] = {};
    const float* hb = h + (size_t)b * bstride;
    for (int c0 = 0; c0 < C; c0 += 8) {
#pragma unroll
        for (int q = 0; q < 2; ++q) {
            int e = t + q * 256;
            int oo = e >> 3, cc = e & 7;
            int r = o0 + oo;
            float v = 0.f;
            if (c0 + cc < C) {
                if (r < O) {
                    v = W[(size_t)r * 2 * C + c0 + cc];
                } else {
                    const float* wr = W + (size_t)(r - O) * 2 * C;
                    v = wr[C + c0 + cc] - wr[c0 + cc];
                }
            }
            Ws[cc][oo] = v;
        }
        {
            int cc = t >> 5, nn4 = t & 31;
            float4 v = make_float4(0.f, 0.f, 0.f, 0.f);
            if (c0 + cc < C) v = *(const float4*)&hb[(size_t)(c0 + cc) * NV + n0 + nn4 * 4];
            *(float4*)&Hs[cc][nn4 * 4] = v;
        }
        __syncthreads();
#pragma unroll
        for (int c = 0; c < 8; ++c) {
            float4 wv = *(const float4*)&Ws[c][ty * 4];
            float ar[4] = {wv.x, wv.y, wv.z, wv.w};
            float br[8];
            float4 h0 = *(const float4*)&Hs[c][tx * 4];
            float4 h1 = *(const float4*)&Hs[c][64 + tx * 4];
            br[0] = h0.x; br[1] = h0.y; br[2] = h0.z; br[3] = h0.w;
            br[4] = h1.x; br[5] = h1.y; br[6] = h1.z; br[7] = h1.w;
#pragma unroll
            for (int a = 0; a < 4; ++a)
#pragma unroll
                for (int q = 0; q < 8; ++q) acc[a][q] += ar[a] * br[q];
        }
        __syncthreads();
    }
#pragma unroll
    for (int a = 0; a < 4; ++a) {
        int o = o0 + ty * 4 + a;
        float* outp = out + ((size_t)b * 2 * O + o) * NV + n0;
        float4 s0 = make_float4(acc[a][0], acc[a][1], acc[a][2], acc[a][3]);
        float4 s1 = make_float4(acc[a][4], acc[a][5], acc[a][6], acc[a][7]);
        *(float4*)&outp[tx * 4] = s0;
        *(float4*)&outp[64 + tx * 4] = s1;
    }
}

// ---------- h_out[b][o][n] = mean_k lrelu( a*(p[b][o][idx[n][k]] + d[b][o][n]) + c0 )
__global__ __launch_bounds__(256) void k_edge(const float* __restrict__ pd,
                                              const int* __restrict__ idx,
                                              const float* __restrict__ ga, const float* __restrict__ be,
                                              const float* __restrict__ mu, const float* __restrict__ va,
                                              float* __restrict__ out, int out_bstride, int O) {
    const int b = blockIdx.x;
    const int n = blockIdx.y * 256 + threadIdx.x;
    const int o0 = blockIdx.z * 4;
    const int* ip = idx + ((size_t)b * NV + n) * KNN;
    int jj[KNN];
#pragma unroll
    for (int k = 0; k < KNN; ++k) jj[k] = ip[k];
#pragma unroll
    for (int a = 0; a < 4; ++a) {
        const int o = o0 + a;
        const float al = ga[o] / sqrtf(va[o] + 1e-5f);
        const float c0 = be[o] - mu[o] * al;
        const float* pb = pd + ((size_t)b * 2 * O + o) * NV;
        const float dv  = pd[((size_t)b * 2 * O + O + o) * NV + n];
        float s = 0.f;
#pragma unroll
        for (int k = 0; k < KNN; ++k) {
            float y = fmaf(al, pb[jj[k]] + dv, c0);
            s += (y > 0.f) ? y : 0.2f * y;
        }
        out[(size_t)b * out_bstride + (size_t)o * NV + n] = s * (1.f / KNN);
    }
}

// ---------- pooled[b][o] = mean_n hf[b][o][n]
__global__ __launch_bounds__(256) void k_pool(const float* __restrict__ hf, float* __restrict__ pooled) {
    const int o = blockIdx.x, b = blockIdx.y;
    const float* hp = hf + ((size_t)b * 512 + o) * NV;
    float s = 0.f;
    for (int i = threadIdx.x; i < NV; i += 256) s += hp[i];
#pragma unroll
    for (int off = 32; off > 0; off >>= 1) s += __shfl_down(s, off, 64);
    __shared__ float red[4];
    if ((threadIdx.x & 63) == 0) red[threadIdx.x >> 6] = s;
    __syncthreads();
    if (threadIdx.x == 0)
        pooled[(size_t)b * 512 + o] = (red[0] + red[1] + red[2] + red[3]) * (1.f / NV);
}

// ---------- out[b][j] = sum_o pooled[b][o] * We[j][o]
__global__ __launch_bounds__(256) void k_final(const float* __restrict__ pooled, const float* __restrict__ We,
                                               float* __restrict__ out) {
    const int j = threadIdx.x, b = blockIdx.x;
    __shared__ float ps[512];
    for (int o = threadIdx.x; o < 512; o += 256) ps[o] = pooled[b * 512 + o];
    __syncthreads();
    float s = 0.f;
    for (int o = 0; o < 512; ++o) s += ps[o] * We[(size_t)j * 512 + o];
    out[b * 256 + j] = s;
}

extern "C" void kernel_launch(void* const* d_in, const int* in_sizes, int n_in,
                              void* d_out, int out_size, void* d_ws, size_t ws_size,
                              hipStream_t stream) {
    const float* x  = (const float*)d_in[0];
    const float* W0 = (const float*)d_in[1];
    const float* g0 = (const float*)d_in[2];
    const float* b0 = (const float*)d_in[3];
    const float* m0 = (const float*)d_in[4];
    const float* v0 = (const float*)d_in[5];
    const float* W1 = (const float*)d_in[6];
    const float* g1 = (const float*)d_in[7];
    const float* b1 = (const float*)d_in[8];
    const float* m1 = (const float*)d_in[9];
    const float* v1 = (const float*)d_in[10];
    const float* W2 = (const float*)d_in[11];
    const float* g2 = (const float*)d_in[12];
    const float* b2 = (const float*)d_in[13];
    const float* m2 = (const float*)d_in[14];
    const float* v2 = (const float*)d_in[15];
    const float* Wf = (const float*)d_in[16];
    const float* gf = (const float*)d_in[17];
    const float* bf = (const float*)d_in[18];
    const float* mf = (const float*)d_in[19];
    const float* vf = (const float*)d_in[20];
    const float* We = (const float*)d_in[21];

    float* ws = (float*)d_ws;
    float* hx     = ws;                          // 24576
    float* cat    = hx + 24576;                  // 3670016
    float* xx     = cat + 3670016;               // 8192
    int*   idx    = (int*)(xx + 8192);           // 163840 ints
    float* pd     = (float*)(idx + 163840);      // 8388608 (2O max = 1024)
    float* hf     = pd + 8388608;                // 4194304
    float* pooled = hf + 4194304;                // 4096

    k_transpose<<<96, 256, 0, stream>>>(x, hx);

    auto run_layer = [&](const float* h, int C, int bstride, const float* W,
                         const float* g, const float* be, const float* m, const float* v,
                         int O, float* outp, int obstride, bool jsplit) {
        k_xx<<<32, 256, 0, stream>>>(h, xx, C, bstride);
        if (jsplit)
            k_knnS<<<512, 512, 0, stream>>>(h, xx, C, bstride, idx);
        else
            k_knnF<<<512, 512, 0, stream>>>(h, xx, C, bstride, idx);
        k_gemm<<<dim3(8, 8, 2 * O / 64), 256, 0, stream>>>(W, O, h, bstride, C, pd);
        k_edge<<<dim3(8, 4, O / 4), 256, 0, stream>>>(pd, idx, g, be, m, v, outp, obstride, O);
    };

    run_layer(hx, 3, 3 * NV, W0, g0, b0, m0, v0, 64, cat, 448 * NV, false);
    run_layer(cat, 64, 448 * NV, W1, g1, b1, m1, v1, 128, cat + 64 * NV, 448 * NV, false);
    run_layer(cat + 64 * NV, 128, 448 * NV, W2, g2, b2, m2, v2, 256, cat + 192 * NV, 448 * NV, false);
    run_layer(cat, 448, 448 * NV, Wf, gf, bf, mf, vf, 512, hf, 512 * NV, true);

    k_pool<<<dim3(512, 8), 256, 0, stream>>>(hf, pooled);
    k_final<<<8, 256, 0, stream>>>(pooled, We, (float*)d_out);
}

// Round 19
// 767.885 us; speedup vs baseline: 1.3827x; 1.3827x over previous
//
#include <hip/hip_runtime.h>
#include <cstdint>

#define KNN 20
#define BV 8
#define NV 1024

// ---- DPP wave64 reduces (rocPRIM pattern): result broadcast via readlane 63.
template <int CTRL>
__device__ __forceinline__ float dppmaxf(float x) {
    int xi = __float_as_int(x);
    int mi = __builtin_amdgcn_update_dpp(xi, xi, CTRL, 0xf, 0xf, false);
    return fmaxf(x, __int_as_float(mi));
}
template <int CTRL>
__device__ __forceinline__ unsigned dppmin(unsigned x) {
    unsigned m = (unsigned)__builtin_amdgcn_update_dpp((int)x, (int)x, CTRL, 0xf, 0xf, false);
    return (x < m) ? x : m;
}
__device__ __forceinline__ float wave_max_f32(float x) {
    x = dppmaxf<0xB1>(x); x = dppmaxf<0x4E>(x); x = dppmaxf<0x141>(x);
    x = dppmaxf<0x140>(x); x = dppmaxf<0x142>(x); x = dppmaxf<0x143>(x);
    return __int_as_float(__builtin_amdgcn_readlane(__float_as_int(x), 63));
}
__device__ __forceinline__ unsigned wave_min_u32(unsigned x) {
    x = dppmin<0xB1>(x); x = dppmin<0x4E>(x); x = dppmin<0x141>(x);
    x = dppmin<0x140>(x); x = dppmin<0x142>(x); x = dppmin<0x143>(x);
    return (unsigned)__builtin_amdgcn_readlane((int)x, 63);
}

// ---------- transpose x [B,N,3] -> hx [B,3,N]
__global__ __launch_bounds__(256) void k_transpose(const float* __restrict__ x, float* __restrict__ hx) {
    int id = blockIdx.x * 256 + threadIdx.x;
    if (id >= BV * 3 * NV) return;
    int n = id % NV;
    int c = (id / NV) % 3;
    int b = id / (3 * NV);
    hx[id] = x[(b * NV + n) * 3 + c];
}

// ---------- xx[b][n] = sum_c h[b][c][n]^2
__global__ __launch_bounds__(256) void k_xx(const float* __restrict__ h, float* __restrict__ xx,
                                            int C, int bstride) {
    int id = blockIdx.x * 256 + threadIdx.x;
    int n = id % NV, b = id / NV;
    if (b >= BV) return;
    const float* hp = h + (size_t)b * bstride + n;
    float s = 0.f;
    for (int c = 0; c < C; ++c) { float v = hp[(size_t)c * NV]; s += v * v; }
    xx[b * NV + n] = s;
}

// ---------- FUSED kNN, FULL ROW (R13 structure, A-from-LDS): block = 16 rows x 1024 cols.
// grid 512 (2 blocks/CU): b = bx&7 (XCD-local), tile = bx>>3. block 512 = 8 waves; wave w
// owns rows i0+2w..+1; lane owns 16 cands at j = g*256 + lane*4 + e (conflict-free b128).
__global__ __launch_bounds__(512, 2) void k_knn(const float* __restrict__ h, const float* __restrict__ xx,
                                                int C, int bstride, int* __restrict__ idx) {
    __shared__ float Bs[8][1024];
    const int bx = blockIdx.x;
    const int b = bx & 7, tile = bx >> 3;
    const int i0 = tile * 16;
    const int t = threadIdx.x, lane = t & 63, w = t >> 6;
    const int irow = i0 + w * 2;
    float acc[2][16] = {};
    const float* hb = h + (size_t)b * bstride;

    for (int c0 = 0; c0 < C; c0 += 8) {
        __syncthreads();
#pragma unroll
        for (int r = 0; r < 4; ++r) {               // Bs[8][1024] = 2048 float4 granules
            int e = r * 512 + t;
            int cc = e >> 8, jj = e & 255;
            float4 v = make_float4(0.f, 0.f, 0.f, 0.f);
            if (c0 + cc < C) v = *(const float4*)&hb[(size_t)(c0 + cc) * NV + jj * 4];
            *(float4*)&Bs[cc][jj * 4] = v;
        }
        __syncthreads();
#pragma unroll
        for (int c = 0; c < 8; ++c) {
            float2 arv = *(const float2*)&Bs[c][irow];     // wave-uniform b64 broadcast
            float ar[2] = {arv.x, arv.y};
            float br[16];
#pragma unroll
            for (int g = 0; g < 4; ++g) {
                float4 bv = *(const float4*)&Bs[c][g * 256 + (lane << 2)];  // 16B/lane: conflict-free
                br[g * 4 + 0] = bv.x; br[g * 4 + 1] = bv.y;
                br[g * 4 + 2] = bv.z; br[g * 4 + 3] = bv.w;
            }
#pragma unroll
            for (int a = 0; a < 2; ++a)
#pragma unroll
                for (int q = 0; q < 16; ++q) acc[a][q] += ar[a] * br[q];
        }
    }

    // neg sqdist in place: bigger = nearer
    const float* xb = xx + b * NV;
    float xxj[16];
#pragma unroll
    for (int g = 0; g < 4; ++g) {
        float4 xv = *(const float4*)&xb[g * 256 + (lane << 2)];
        xxj[g * 4 + 0] = xv.x; xxj[g * 4 + 1] = xv.y;
        xxj[g * 4 + 2] = xv.z; xxj[g * 4 + 3] = xv.w;
    }
#pragma unroll
    for (int a = 0; a < 2; ++a) {
        float xi = xb[irow + a];
#pragma unroll
        for (int q = 0; q < 16; ++q) acc[a][q] = 2.f * acc[a][q] - xi - xxj[q];
    }

    // ---- wave-parallel top-20 per row, 2 rows interleaved, float compares.
    int* opb = idx + ((size_t)(b * NV + irow)) * KNN;
#pragma unroll 1
    for (int s = 0; s < KNN; ++s) {
#pragma unroll
        for (int a = 0; a < 2; ++a) {
            // 16-wide tournament tree; strict > keeps lower q; j(q) monotone in q
            float w0[8]; int p0[8];
#pragma unroll
            for (int i = 0; i < 8; ++i) {
                bool g = acc[a][2 * i + 1] > acc[a][2 * i];
                w0[i] = g ? acc[a][2 * i + 1] : acc[a][2 * i];
                p0[i] = g ? 2 * i + 1 : 2 * i;
            }
            float w1[4]; int p1[4];
#pragma unroll
            for (int i = 0; i < 4; ++i) {
                bool g = w0[2 * i + 1] > w0[2 * i];
                w1[i] = g ? w0[2 * i + 1] : w0[2 * i];
                p1[i] = g ? p0[2 * i + 1] : p0[2 * i];
            }
            float w2[2]; int p2[2];
#pragma unroll
            for (int i = 0; i < 2; ++i) {
                bool g = w1[2 * i + 1] > w1[2 * i];
                w2[i] = g ? w1[2 * i + 1] : w1[2 * i];
                p2[i] = g ? p1[2 * i + 1] : p1[2 * i];
            }
            bool gf = w2[1] > w2[0];
            float bv = gf ? w2[1] : w2[0];
            int bq = gf ? p2[1] : p2[0];

            float gmax = wave_max_f32(bv);
            int myj = ((bq >> 2) << 8) + (lane << 2) + (bq & 3);
            unsigned cand = (bv == gmax) ? (unsigned)myj : 0xFFFFFFFFu;
            int j = (int)wave_min_u32(cand);            // exact lowest-j among value ties
            if (lane == 0) opb[a * KNN + s] = j;
            int wq = (cand == (unsigned)j) ? bq : 99;   // unique winner poisons its slot
#pragma unroll
            for (int q = 0; q < 16; ++q)
                if (wq == q) acc[a][q] = -3.4e38f;
        }
    }
}

// ---------- pd[b][r][n] = sum_c A[r][c]*h[b][c][n], A packed inline from W:
// r<O: Wl row; r>=O: (Wr-Wl) row.   64x128 tile, 4x8 micro.
__global__ __launch_bounds__(256) void k_gemm(const float* __restrict__ W, int O,
                                              const float* __restrict__ h, int bstride, int C,
                                              float* __restrict__ out) {
    __shared__ float Ws[8][64], Hs[8][128];
    const int b = blockIdx.x, n0 = blockIdx.y * 128, o0 = blockIdx.z * 64;
    const int t = threadIdx.x, tx = t & 15, ty = t >> 4;
    float acc[4][8] = {};
    const float* hb = h + (size_t)b * bstride;
    for (int c0 = 0; c0 < C; c0 += 8) {
#pragma unroll
        for (int q = 0; q < 2; ++q) {
            int e = t + q * 256;
            int oo = e >> 3, cc = e & 7;
            int r = o0 + oo;
            float v = 0.f;
            if (c0 + cc < C) {
                if (r < O) {
                    v = W[(size_t)r * 2 * C + c0 + cc];
                } else {
                    const float* wr = W + (size_t)(r - O) * 2 * C;
                    v = wr[C + c0 + cc] - wr[c0 + cc];
                }
            }
            Ws[cc][oo] = v;
        }
        {
            int cc = t >> 5, nn4 = t & 31;
            float4 v = make_float4(0.f, 0.f, 0.f, 0.f);
            if (c0 + cc < C) v = *(const float4*)&hb[(size_t)(c0 + cc) * NV + n0 + nn4 * 4];
            *(float4*)&Hs[cc][nn4 * 4] = v;
        }
        __syncthreads();
#pragma unroll
        for (int c = 0; c < 8; ++c) {
            float4 wv = *(const float4*)&Ws[c][ty * 4];
            float ar[4] = {wv.x, wv.y, wv.z, wv.w};
            float br[8];
            float4 h0 = *(const float4*)&Hs[c][tx * 4];
            float4 h1 = *(const float4*)&Hs[c][64 + tx * 4];
            br[0] = h0.x; br[1] = h0.y; br[2] = h0.z; br[3] = h0.w;
            br[4] = h1.x; br[5] = h1.y; br[6] = h1.z; br[7] = h1.w;
#pragma unroll
            for (int a = 0; a < 4; ++a)
#pragma unroll
                for (int q = 0; q < 8; ++q) acc[a][q] += ar[a] * br[q];
        }
        __syncthreads();
    }
#pragma unroll
    for (int a = 0; a < 4; ++a) {
        int o = o0 + ty * 4 + a;
        float* outp = out + ((size_t)b * 2 * O + o) * NV + n0;
        float4 s0 = make_float4(acc[a][0], acc[a][1], acc[a][2], acc[a][3]);
        float4 s1 = make_float4(acc[a][4], acc[a][5], acc[a][6], acc[a][7]);
        *(float4*)&outp[tx * 4] = s0;
        *(float4*)&outp[64 + tx * 4] = s1;
    }
}

// ---------- LDS-staged edge: h_out[b][o][n] = mean_k lrelu(a*(p[o][idx[n][k]] + d[o][n]) + c0)
// grid 8*O/4 (1D, b = bx&7 XCD-local, o-group = bx>>3): block stages Ps[4][1024] (16 KB,
// coalesced, once) then gathers from LDS — kills the 64B-line L2 amplification of the
// old per-thread global gathers (~10 GB L2 traffic -> 630 MB LDS traffic).
__global__ __launch_bounds__(256) void k_edge(const float* __restrict__ pd,
                                              const int* __restrict__ idx,
                                              const float* __restrict__ ga, const float* __restrict__ be,
                                              const float* __restrict__ mu, const float* __restrict__ va,
                                              float* __restrict__ out, int out_bstride, int O) {
    __shared__ float Ps[4][1024];
    const int bx = blockIdx.x;
    const int b = bx & 7, o0 = (bx >> 3) * 4;
    const int t = threadIdx.x;
    const float* pbase = pd + ((size_t)b * 2 * O + o0) * NV;
#pragma unroll
    for (int r = 0; r < 4; ++r) {                 // stage 4 p-rows, coalesced float4
        float4 v = *(const float4*)&pbase[(size_t)r * NV + t * 4];
        *(float4*)&Ps[r][t * 4] = v;
    }
    float al[4], cc[4];
#pragma unroll
    for (int a = 0; a < 4; ++a) {
        al[a] = ga[o0 + a] / sqrtf(va[o0 + a] + 1e-5f);
        cc[a] = be[o0 + a] - mu[o0 + a] * al[a];
    }
    __syncthreads();
    const float* dbase = pd + ((size_t)b * 2 * O + O + o0) * NV;
    float* obase = out + (size_t)b * out_bstride + (size_t)o0 * NV;
#pragma unroll
    for (int nc = 0; nc < 4; ++nc) {
        int n = nc * 256 + t;
        const int* ip = idx + ((size_t)b * NV + n) * KNN;
        int jj[KNN];
#pragma unroll
        for (int k = 0; k < KNN; ++k) jj[k] = ip[k];
#pragma unroll
        for (int a = 0; a < 4; ++a) {
            float dv = dbase[(size_t)a * NV + n];
            float s = 0.f;
#pragma unroll
            for (int k = 0; k < KNN; ++k) {
                float y = fmaf(al[a], Ps[a][jj[k]] + dv, cc[a]);
                s += (y > 0.f) ? y : 0.2f * y;
            }
            obase[(size_t)a * NV + n] = s * (1.f / KNN);
        }
    }
}

// ---------- pooled[b][o] = mean_n hf[b][o][n]
__global__ __launch_bounds__(256) void k_pool(const float* __restrict__ hf, float* __restrict__ pooled) {
    const int o = blockIdx.x, b = blockIdx.y;
    const float* hp = hf + ((size_t)b * 512 + o) * NV;
    float s = 0.f;
    for (int i = threadIdx.x; i < NV; i += 256) s += hp[i];
#pragma unroll
    for (int off = 32; off > 0; off >>= 1) s += __shfl_down(s, off, 64);
    __shared__ float red[4];
    if ((threadIdx.x & 63) == 0) red[threadIdx.x >> 6] = s;
    __syncthreads();
    if (threadIdx.x == 0)
        pooled[(size_t)b * 512 + o] = (red[0] + red[1] + red[2] + red[3]) * (1.f / NV);
}

// ---------- out[b][j] = sum_o pooled[b][o] * We[j][o]
__global__ __launch_bounds__(256) void k_final(const float* __restrict__ pooled, const float* __restrict__ We,
                                               float* __restrict__ out) {
    const int j = threadIdx.x, b = blockIdx.x;
    __shared__ float ps[512];
    for (int o = threadIdx.x; o < 512; o += 256) ps[o] = pooled[b * 512 + o];
    __syncthreads();
    float s = 0.f;
    for (int o = 0; o < 512; ++o) s += ps[o] * We[(size_t)j * 512 + o];
    out[b * 256 + j] = s;
}

extern "C" void kernel_launch(void* const* d_in, const int* in_sizes, int n_in,
                              void* d_out, int out_size, void* d_ws, size_t ws_size,
                              hipStream_t stream) {
    const float* x  = (const float*)d_in[0];
    const float* W0 = (const float*)d_in[1];
    const float* g0 = (const float*)d_in[2];
    const float* b0 = (const float*)d_in[3];
    const float* m0 = (const float*)d_in[4];
    const float* v0 = (const float*)d_in[5];
    const float* W1 = (const float*)d_in[6];
    const float* g1 = (const float*)d_in[7];
    const float* b1 = (const float*)d_in[8];
    const float* m1 = (const float*)d_in[9];
    const float* v1 = (const float*)d_in[10];
    const float* W2 = (const float*)d_in[11];
    const float* g2 = (const float*)d_in[12];
    const float* b2 = (const float*)d_in[13];
    const float* m2 = (const float*)d_in[14];
    const float* v2 = (const float*)d_in[15];
    const float* Wf = (const float*)d_in[16];
    const float* gf = (const float*)d_in[17];
    const float* bf = (const float*)d_in[18];
    const float* mf = (const float*)d_in[19];
    const float* vf = (const float*)d_in[20];
    const float* We = (const float*)d_in[21];

    float* ws = (float*)d_ws;
    float* hx     = ws;                          // 24576
    float* cat    = hx + 24576;                  // 3670016
    float* xx     = cat + 3670016;               // 8192
    int*   idx    = (int*)(xx + 8192);           // 163840 ints
    float* pd     = (float*)(idx + 163840);      // 8388608 (2O max = 1024)
    float* hf     = pd + 8388608;                // 4194304
    float* pooled = hf + 4194304;                // 4096

    k_transpose<<<96, 256, 0, stream>>>(x, hx);

    auto run_layer = [&](const float* h, int C, int bstride, const float* W,
                         const float* g, const float* be, const float* m, const float* v,
                         int O, float* outp, int obstride) {
        k_xx<<<32, 256, 0, stream>>>(h, xx, C, bstride);
        k_knn<<<512, 512, 0, stream>>>(h, xx, C, bstride, idx);
        k_gemm<<<dim3(8, 8, 2 * O / 64), 256, 0, stream>>>(W, O, h, bstride, C, pd);
        k_edge<<<8 * O / 4, 256, 0, stream>>>(pd, idx, g, be, m, v, outp, obstride, O);
    };

    run_layer(hx, 3, 3 * NV, W0, g0, b0, m0, v0, 64, cat, 448 * NV);
    run_layer(cat, 64, 448 * NV, W1, g1, b1, m1, v1, 128, cat + 64 * NV, 448 * NV);
    run_layer(cat + 64 * NV, 128, 448 * NV, W2, g2, b2, m2, v2, 256, cat + 192 * NV, 448 * NV);
    run_layer(cat, 448, 448 * NV, Wf, gf, bf, mf, vf, 512, hf, 512 * NV);

    k_pool<<<dim3(512, 8), 256, 0, stream>>>(hf, pooled);
    k_final<<<8, 256, 0, stream>>>(pooled, We, (float*)d_out);
}